// Round 8
// baseline (434.038 us; speedup 1.0000x reference)
//
#include <hip/hip_runtime.h>
#include <hip/hip_bf16.h>
#include <math.h>

#define TOKENS 2048
#define HID 2048
#define FFN 1024
#define NEXP 16
#define NTOT 32
#define KSEL 4
#define RSCALE 2.5f
#define ACT_ROWS 10240  // >= max total routed rows (8192) + tile overrun (2047)

typedef __bf16 v8bf __attribute__((ext_vector_type(8)));
typedef __bf16 v4bf __attribute__((ext_vector_type(4)));
typedef float v4f __attribute__((ext_vector_type(4)));

// Swizzled LDS addressing: row-major [rows][64] bf16 (128B rows, 8 chunks of
// 16B). Physical chunk = chunk ^ (row&7). Conflict-free on b128 frag reads
// (SQ_LDS_BANK_CONFLICT == 0, rounds 2-6).
static __device__ __forceinline__ int swz(int row, int chunk) {
  return (row << 6) + ((((unsigned)(chunk ^ row)) & 7u) << 3);
}

// Async 16B global->LDS DMA (no VGPR roundtrip). LDS dest is wave-uniform
// base + lane*16 (linear); we pre-swizzle the per-lane SOURCE instead
// (guide rule #21: linear dest + inverse-swz source + swz on read).
static __device__ __forceinline__ void async_copy16(const __bf16* g,
                                                    __bf16* l) {
  __builtin_amdgcn_global_load_lds(
      (const __attribute__((address_space(1))) unsigned int*)g,
      (__attribute__((address_space(3))) unsigned int*)l, 16, 0, 0);
}

// ---------------------------------------------------------------------------
// Router: one block per token. Exact fp32 logits -> softmax -> bias-corrected
// top-4 (lowest-index tie-break), zero-expert folding, writes
// out = zero_total*x, bf16 hidden copy, per-expert (token,weight) lists.
// ---------------------------------------------------------------------------
__global__ __launch_bounds__(256) void router_kernel(
    const float* __restrict__ hidden, const float* __restrict__ rw,
    const float* __restrict__ bias, float* __restrict__ out,
    __bf16* __restrict__ hbf,
    int* __restrict__ counts, int* __restrict__ pair_token,
    float* __restrict__ pair_weight)
{
  const int t = blockIdx.x;
  const int tid = threadIdx.x;
  __shared__ float sh[HID];
  __shared__ float part[8][NTOT];
  __shared__ float s_zt;

  const float* hrow = hidden + (size_t)t * HID;
  for (int i = tid; i < HID / 4; i += 256)
    ((float4*)sh)[i] = ((const float4*)hrow)[i];
  __syncthreads();

  {
    const int base = tid * 8;
    v8bf v;
#pragma unroll
    for (int j = 0; j < 8; ++j) v[j] = (__bf16)sh[base + j];
    *(v8bf*)(hbf + (size_t)t * HID + base) = v;
  }

  {
    const int g = tid >> 5, e = tid & 31;
    const float* w = rw + (size_t)e * HID + g * 256;
    const float* hh = sh + g * 256;
    float acc = 0.f;
#pragma unroll 8
    for (int h = 0; h < 256; ++h) acc = fmaf(hh[h], w[h], acc);
    part[g][e] = acc;
  }
  __syncthreads();

  if (tid < 64) {
    const int lane = tid;
    float logit = -INFINITY;
    if (lane < NTOT) {
      float s = 0.f;
#pragma unroll
      for (int g = 0; g < 8; ++g) s += part[g][lane];
      logit = s;
    }
    float m = logit;
#pragma unroll
    for (int off = 32; off; off >>= 1) m = fmaxf(m, __shfl_xor(m, off));
    const float ex = (lane < NTOT) ? expf(logit - m) : 0.f;
    float sum = ex;
#pragma unroll
    for (int off = 32; off; off >>= 1) sum += __shfl_xor(sum, off);
    float sc = (lane < NTOT) ? (ex / sum + bias[lane]) : -INFINITY;

    float zt = 0.f;
#pragma unroll
    for (int it = 0; it < KSEL; ++it) {
      float v = sc; int vid = lane;
#pragma unroll
      for (int off = 32; off; off >>= 1) {
        const float ov = __shfl_xor(v, off);
        const int oid = __shfl_xor(vid, off);
        if (ov > v || (ov == v && oid < vid)) { v = ov; vid = oid; }
      }
      const float wv = v * RSCALE;
      if (vid >= NEXP) {
        zt += wv;
      } else if (lane == 0) {
        const int pos = atomicAdd(&counts[vid], 1);
        pair_token[vid * TOKENS + pos] = t;
        pair_weight[vid * TOKENS + pos] = wv;
      }
      if (lane == vid) sc = -INFINITY;
    }
    if (lane == 0) s_zt = zt;
  }
  __syncthreads();

  const float zt = s_zt;
  float* orow = out + (size_t)t * HID;
  for (int i = tid; i < HID / 4; i += 256) {
    float4 v = ((const float4*)sh)[i];
    v.x *= zt; v.y *= zt; v.z *= zt; v.w *= zt;
    ((float4*)orow)[i] = v;
  }
}

// ---------------------------------------------------------------------------
__global__ void scan_kernel(const int* __restrict__ counts,
                            int* __restrict__ offsets) {
  if (threadIdx.x == 0) {
    int acc = 0;
#pragma unroll
    for (int e = 0; e < NEXP; ++e) { offsets[e] = acc; acc += counts[e]; }
    offsets[NEXP] = acc;
  }
}

// ---------------------------------------------------------------------------
// Weight transpose+convert: src [e][R][C] fp32 -> dst [e][C][R] bf16.
// 64x64 tile per block, LDS-transposed (swizzled chunks), coalesced both ways.
// Pure streaming, BW-bound.
// ---------------------------------------------------------------------------
__global__ __launch_bounds__(256) void transpose_cvt_kernel(
    const float* __restrict__ src, __bf16* __restrict__ dst, int R, int C)
{
  const int e = blockIdx.z, rt = blockIdx.y, ct = blockIdx.x;
  __shared__ __bf16 sT[64 * 64];  // logical [f][k], swz chunks

  const int tid = threadIdx.x;
  const int km = tid >> 4, fm = tid & 15;   // 4k x 4f micro-tile per thread
  const int k0 = km * 4, f0 = fm * 4;

  const float* s = src + (size_t)e * R * C + (size_t)(rt * 64 + k0) * C
                 + ct * 64 + f0;
  v4f v[4];
#pragma unroll
  for (int i = 0; i < 4; ++i)
    v[i] = *(const v4f*)(s + (size_t)i * C);

#pragma unroll
  for (int j = 0; j < 4; ++j) {
    v4bf c;
#pragma unroll
    for (int i = 0; i < 4; ++i) c[i] = (__bf16)v[i][j];
    // logical [f0+j][k0..k0+3]; chunk = k0>>3, half offset = k0&4
    *(v4bf*)&sT[swz(f0 + j, k0 >> 3) + (k0 & 4)] = c;
  }
  __syncthreads();

  const int f = tid >> 2, kc = tid & 3;
  const v8bf o0 = *(const v8bf*)&sT[swz(f, kc * 2)];
  const v8bf o1 = *(const v8bf*)&sT[swz(f, kc * 2 + 1)];
  __bf16* d = dst + (size_t)e * C * R + (size_t)(ct * 64 + f) * R
            + rt * 64 + kc * 16;
  *(v8bf*)d = o0;
  *(v8bf*)(d + 8) = o1;
}

// ---------------------------------------------------------------------------
// GEMM1 (grouped): tile = 128 gathered rows x 32 f (gate+up -> 64 B-rows),
// BK=64, double-buffered LDS, global_load_lds staging (async DMA issued
// before compute, one barrier/iter). Group (e,ft) XCD-pinned, mt dense.
// Working ~1024 blocks; LDS 49KB -> 3 blocks/CU.
// ---------------------------------------------------------------------------
__global__ __launch_bounds__(256, 3) void gemm1_kernel(
    const __bf16* __restrict__ hbf, const __bf16* __restrict__ w13t,
    const int* __restrict__ counts, const int* __restrict__ offsets,
    const int* __restrict__ pair_token, const float* __restrict__ pair_weight,
    __bf16* __restrict__ act)
{
  const int lin = blockIdx.x;
  const int xcd = lin & 7;
  const int q = lin >> 3;            // 0..1023
  const int mt = q & 15;             // dense: 16 m-tiles of 128
  const int g = (q >> 4) * 8 + xcd;  // 0..511 = (e, ft)
  const int ft = g & 31;
  const int e = g >> 5;

  const int cnt = counts[e];
  const int m0 = mt * 128;
  if (m0 >= cnt) return;
  const int obase = offsets[e];
  const int fbase = ft * 32;

  __shared__ __bf16 sA[2][128 * 64];  // 2 x 16 KB
  __shared__ __bf16 sB[2][64 * 64];   // 2 x 8 KB; rows 0-31 gate, 32-63 up
  __shared__ int sTok[128];
  __shared__ float sW[128];

  const int tid = threadIdx.x;
  if (tid < 128) {
    const int m = m0 + tid;
    sTok[tid] = (m < cnt) ? pair_token[e * TOKENS + m] : 0;  // dummy row 0
    sW[tid] = (m < cnt) ? pair_weight[e * TOKENS + m] : 0.f;
  }
  __syncthreads();

  const int wid = tid >> 6, lane = tid & 63;
  const int wr = wid >> 1, wf = wid & 1;
  const int lrow = lane & 15, lq = lane >> 4;

  // Per-lane DMA source pointers, pre-swizzled; LDS dest linear per slot.
  // A: 16KB = 1024 slots of 16B -> 4 instrs/thread. B: 8KB -> 2.
  const __bf16* gA[4];
  int ldsA[4];
#pragma unroll
  for (int i = 0; i < 4; ++i) {
    const int s = (wid * 4 + i) * 64 + lane;
    const int row = s >> 3, ch = s & 7;
    gA[i] = hbf + (size_t)sTok[row] * HID + (ch ^ (row & 7)) * 8;
    ldsA[i] = (wid * 4 + i) * 512;
  }
  const __bf16* gB[2];
  int ldsB[2];
  const __bf16* w13e = w13t + (size_t)e * (2 * FFN) * HID;
#pragma unroll
  for (int i = 0; i < 2; ++i) {
    const int s = (wid * 2 + i) * 64 + lane;
    const int row = s >> 3, ch = s & 7;
    const int fp = (row < 32) ? (fbase + row) : (FFN + fbase + (row - 32));
    gB[i] = w13e + (size_t)fp * HID + (ch ^ (row & 7)) * 8;
    ldsB[i] = (wid * 2 + i) * 512;
  }

  v4f accg[4], accu[4];
#pragma unroll
  for (int mi = 0; mi < 4; ++mi) {
    v4f z = {0.f, 0.f, 0.f, 0.f};
    accg[mi] = z; accu[mi] = z;
  }

#define G1_STAGE(buf_)                                                  \
  {                                                                     \
    _Pragma("unroll") for (int i = 0; i < 4; ++i) {                     \
      async_copy16(gA[i], &sA[buf_][ldsA[i]]); gA[i] += 64;             \
    }                                                                   \
    _Pragma("unroll") for (int i = 0; i < 2; ++i) {                     \
      async_copy16(gB[i], &sB[buf_][ldsB[i]]); gB[i] += 64;             \
    }                                                                   \
  }

  G1_STAGE(0);
  __syncthreads();  // drains vmcnt(0): tile 0 ready

  int buf = 0;
  for (int t = 0; t < HID / 64; ++t) {
    if (t < HID / 64 - 1) G1_STAGE(buf ^ 1);  // async, flies under compute
#pragma unroll
    for (int ks = 0; ks < 2; ++ks) {
      v8bf a[4];
#pragma unroll
      for (int mi = 0; mi < 4; ++mi)
        a[mi] = *(const v8bf*)&sA[buf][swz(wr * 64 + mi * 16 + lrow, ks * 4 + lq)];
      const v8bf bg = *(const v8bf*)&sB[buf][swz(wf * 16 + lrow, ks * 4 + lq)];
      const v8bf bu = *(const v8bf*)&sB[buf][swz(32 + wf * 16 + lrow, ks * 4 + lq)];
#pragma unroll
      for (int mi = 0; mi < 4; ++mi) {
        accg[mi] = __builtin_amdgcn_mfma_f32_16x16x32_bf16(a[mi], bg, accg[mi], 0, 0, 0);
        accu[mi] = __builtin_amdgcn_mfma_f32_16x16x32_bf16(a[mi], bu, accu[mi], 0, 0, 0);
      }
    }
    __syncthreads();  // all reads of buf done AND next-tile DMA drained
    buf ^= 1;
  }

  // ---- epilogue: swiglu, fold routing weight, store act (bf16) ----
  const int f = fbase + wf * 16 + lrow;
#pragma unroll
  for (int mi = 0; mi < 4; ++mi) {
#pragma unroll
    for (int r = 0; r < 4; ++r) {
      const int lr = wr * 64 + mi * 16 + lq * 4 + r;
      const int m = m0 + lr;
      if (m < cnt) {
        const float gg = accg[mi][r];
        const float uu = accu[mi][r];
        const float sg = gg / (1.f + __expf(-gg));
        act[(size_t)(obase + m) * FFN + f] = (__bf16)(sg * uu * sW[lr]);
      }
    }
  }
#undef G1_STAGE
}

// ---------------------------------------------------------------------------
// GEMM2 (grouped): tile = 128 rows (contiguous act) x 64 n, BK=64, K=1024.
// Same DMA double-buffer structure. atomicAdd into out.
// ---------------------------------------------------------------------------
__global__ __launch_bounds__(256, 3) void gemm2_kernel(
    const __bf16* __restrict__ act, const __bf16* __restrict__ w2t,
    const int* __restrict__ counts, const int* __restrict__ offsets,
    const int* __restrict__ pair_token, float* __restrict__ out)
{
  const int lin = blockIdx.x;
  const int xcd = lin & 7;
  const int q = lin >> 3;            // 0..1023
  const int mt = q & 15;
  const int g = (q >> 4) * 8 + xcd;  // 0..511 = (e, nt)
  const int nt = g & 31;
  const int e = g >> 5;

  const int cnt = counts[e];
  const int m0 = mt * 128;
  if (m0 >= cnt) return;
  const int obase = offsets[e];
  const int n0 = nt * 64;

  __shared__ __bf16 sA[2][128 * 64];
  __shared__ __bf16 sB[2][64 * 64];
  __shared__ int sTok[128];

  const int tid = threadIdx.x;
  if (tid < 128) {
    const int m = m0 + tid;
    sTok[tid] = (m < cnt) ? pair_token[e * TOKENS + m] : -1;
  }
  __syncthreads();

  const int wid = tid >> 6, lane = tid & 63;
  const int wr = wid >> 1, wn = wid & 1;
  const int lrow = lane & 15, lq = lane >> 4;

  const __bf16* gA[4];
  int ldsA[4];
#pragma unroll
  for (int i = 0; i < 4; ++i) {
    const int s = (wid * 4 + i) * 64 + lane;
    const int row = s >> 3, ch = s & 7;
    gA[i] = act + (size_t)(obase + m0 + row) * FFN + (ch ^ (row & 7)) * 8;
    ldsA[i] = (wid * 4 + i) * 512;
  }
  const __bf16* gB[2];
  int ldsB[2];
  const __bf16* w2e = w2t + (size_t)e * HID * FFN;
#pragma unroll
  for (int i = 0; i < 2; ++i) {
    const int s = (wid * 2 + i) * 64 + lane;
    const int row = s >> 3, ch = s & 7;
    gB[i] = w2e + (size_t)(n0 + row) * FFN + (ch ^ (row & 7)) * 8;
    ldsB[i] = (wid * 2 + i) * 512;
  }

  v4f acc[4][2];
#pragma unroll
  for (int mi = 0; mi < 4; ++mi)
#pragma unroll
    for (int ni = 0; ni < 2; ++ni) {
      v4f z = {0.f, 0.f, 0.f, 0.f};
      acc[mi][ni] = z;
    }

#define G2_STAGE(buf_)                                                  \
  {                                                                     \
    _Pragma("unroll") for (int i = 0; i < 4; ++i) {                     \
      async_copy16(gA[i], &sA[buf_][ldsA[i]]); gA[i] += 64;             \
    }                                                                   \
    _Pragma("unroll") for (int i = 0; i < 2; ++i) {                     \
      async_copy16(gB[i], &sB[buf_][ldsB[i]]); gB[i] += 64;             \
    }                                                                   \
  }

  G2_STAGE(0);
  __syncthreads();

  int buf = 0;
  for (int t = 0; t < FFN / 64; ++t) {
    if (t < FFN / 64 - 1) G2_STAGE(buf ^ 1);
#pragma unroll
    for (int ks = 0; ks < 2; ++ks) {
      v8bf a[4], b[2];
#pragma unroll
      for (int mi = 0; mi < 4; ++mi)
        a[mi] = *(const v8bf*)&sA[buf][swz(wr * 64 + mi * 16 + lrow, ks * 4 + lq)];
#pragma unroll
      for (int ni = 0; ni < 2; ++ni)
        b[ni] = *(const v8bf*)&sB[buf][swz(wn * 32 + ni * 16 + lrow, ks * 4 + lq)];
#pragma unroll
      for (int mi = 0; mi < 4; ++mi)
#pragma unroll
        for (int ni = 0; ni < 2; ++ni)
          acc[mi][ni] = __builtin_amdgcn_mfma_f32_16x16x32_bf16(
              a[mi], b[ni], acc[mi][ni], 0, 0, 0);
    }
    __syncthreads();
    buf ^= 1;
  }

  // ---- epilogue: atomicAdd weighted expert output into out ----
#pragma unroll
  for (int mi = 0; mi < 4; ++mi) {
#pragma unroll
    for (int ni = 0; ni < 2; ++ni) {
      const int n = n0 + wn * 32 + ni * 16 + lrow;
#pragma unroll
      for (int r = 0; r < 4; ++r) {
        const int lr = wr * 64 + mi * 16 + lq * 4 + r;
        const int m = m0 + lr;
        if (m < cnt) {
          const int t = sTok[lr];
          atomicAdd(&out[(size_t)t * HID + n], acc[mi][ni][r]);
        }
      }
    }
  }
#undef G2_STAGE
}

// ---------------------------------------------------------------------------
extern "C" void kernel_launch(void* const* d_in, const int* in_sizes, int n_in,
                              void* d_out, int out_size, void* d_ws, size_t ws_size,
                              hipStream_t stream) {
  const float* hidden = (const float*)d_in[0];
  const float* rw     = (const float*)d_in[1];
  const float* bias   = (const float*)d_in[2];
  const float* w13    = (const float*)d_in[3];
  const float* w2     = (const float*)d_in[4];
  float* out = (float*)d_out;

  // workspace layout (~230 MB; ws is ~1 GB per harness fill counters)
  char* ws = (char*)d_ws;
  int* counts = (int*)ws;
  int* offsets = (int*)(ws + 64);
  int* pair_token = (int*)(ws + 256);
  float* pair_weight = (float*)(ws + 256 + (size_t)NEXP * TOKENS * 4);
  __bf16* hbf = (__bf16*)(ws + 256 + 2 * (size_t)NEXP * TOKENS * 4);
  __bf16* act = hbf + (size_t)TOKENS * HID;
  __bf16* w13t = act + (size_t)ACT_ROWS * FFN;
  __bf16* w2t = w13t + (size_t)NEXP * (2 * FFN) * HID;

  hipMemsetAsync(counts, 0, 16 * sizeof(int), stream);
  router_kernel<<<TOKENS, 256, 0, stream>>>(hidden, rw, bias, out, hbf,
                                            counts, pair_token, pair_weight);
  scan_kernel<<<1, 64, 0, stream>>>(counts, offsets);
  // w2 [e][1024][2048] -> w2t [e][2048][1024]
  transpose_cvt_kernel<<<dim3(32, 16, NEXP), 256, 0, stream>>>(w2, w2t, FFN, HID);
  // w13 [e][2048][2048] -> w13t [e][2048][2048] (f' rows: 0-1023 gate, 1024+ up)
  transpose_cvt_kernel<<<dim3(32, 32, NEXP), 256, 0, stream>>>(w13, w13t, HID, 2 * FFN);
  // gemm1: 8 xcd x 16 mt x 64 ghi = 8192 (groups = 16e x 32ft)
  gemm1_kernel<<<8192, 256, 0, stream>>>(
      hbf, w13t, counts, offsets, pair_token, pair_weight, act);
  // gemm2: 8 xcd x 16 mt x 64 ghi = 8192 (groups = 16e x 32nt)
  gemm2_kernel<<<8192, 256, 0, stream>>>(
      act, w2t, counts, offsets, pair_token, out);
}

// Round 9
// 400.451 us; speedup vs baseline: 1.0839x; 1.0839x over previous
//
#include <hip/hip_runtime.h>
#include <hip/hip_bf16.h>
#include <math.h>

#define TOKENS 2048
#define HID 2048
#define FFN 1024
#define NEXP 16
#define NTOT 32
#define KSEL 4
#define RSCALE 2.5f
#define ACT_ROWS 10240  // >= max routed rows (8192) + tile overrun

typedef __bf16 v8bf __attribute__((ext_vector_type(8)));
typedef float v4f __attribute__((ext_vector_type(4)));

// Swizzled LDS addressing: row-major [rows][64] bf16 (128B rows, 8 chunks of
// 16B). Physical chunk = chunk ^ (row&7). Conflict-free b128 frag reads
// (SQ_LDS_BANK_CONFLICT == 0, rounds 2-6, 8).
static __device__ __forceinline__ int swz(int row, int chunk) {
  return (row << 6) + ((((unsigned)(chunk ^ row)) & 7u) << 3);
}

// Async 16B global->LDS DMA. LDS dest linear (wave base + lane*16);
// per-lane SOURCE is pre-swizzled (rule #21). Verified correct in round 8.
static __device__ __forceinline__ void async_copy16(const __bf16* g,
                                                    __bf16* l) {
  __builtin_amdgcn_global_load_lds(
      (const __attribute__((address_space(1))) unsigned int*)g,
      (__attribute__((address_space(3))) unsigned int*)l, 16, 0, 0);
}

// ---------------------------------------------------------------------------
// Router: one block per token (unchanged, correct since round 1).
// ---------------------------------------------------------------------------
__global__ __launch_bounds__(256) void router_kernel(
    const float* __restrict__ hidden, const float* __restrict__ rw,
    const float* __restrict__ bias, float* __restrict__ out,
    __bf16* __restrict__ hbf,
    int* __restrict__ counts, int* __restrict__ pair_token,
    float* __restrict__ pair_weight)
{
  const int t = blockIdx.x;
  const int tid = threadIdx.x;
  __shared__ float sh[HID];
  __shared__ float part[8][NTOT];
  __shared__ float s_zt;

  const float* hrow = hidden + (size_t)t * HID;
  for (int i = tid; i < HID / 4; i += 256)
    ((float4*)sh)[i] = ((const float4*)hrow)[i];
  __syncthreads();

  {
    const int base = tid * 8;
    v8bf v;
#pragma unroll
    for (int j = 0; j < 8; ++j) v[j] = (__bf16)sh[base + j];
    *(v8bf*)(hbf + (size_t)t * HID + base) = v;
  }

  {
    const int g = tid >> 5, e = tid & 31;
    const float* w = rw + (size_t)e * HID + g * 256;
    const float* hh = sh + g * 256;
    float acc = 0.f;
#pragma unroll 8
    for (int h = 0; h < 256; ++h) acc = fmaf(hh[h], w[h], acc);
    part[g][e] = acc;
  }
  __syncthreads();

  if (tid < 64) {
    const int lane = tid;
    float logit = -INFINITY;
    if (lane < NTOT) {
      float s = 0.f;
#pragma unroll
      for (int g = 0; g < 8; ++g) s += part[g][lane];
      logit = s;
    }
    float m = logit;
#pragma unroll
    for (int off = 32; off; off >>= 1) m = fmaxf(m, __shfl_xor(m, off));
    const float ex = (lane < NTOT) ? expf(logit - m) : 0.f;
    float sum = ex;
#pragma unroll
    for (int off = 32; off; off >>= 1) sum += __shfl_xor(sum, off);
    float sc = (lane < NTOT) ? (ex / sum + bias[lane]) : -INFINITY;

    float zt = 0.f;
#pragma unroll
    for (int it = 0; it < KSEL; ++it) {
      float v = sc; int vid = lane;
#pragma unroll
      for (int off = 32; off; off >>= 1) {
        const float ov = __shfl_xor(v, off);
        const int oid = __shfl_xor(vid, off);
        if (ov > v || (ov == v && oid < vid)) { v = ov; vid = oid; }
      }
      const float wv = v * RSCALE;
      if (vid >= NEXP) {
        zt += wv;
      } else if (lane == 0) {
        const int pos = atomicAdd(&counts[vid], 1);
        pair_token[vid * TOKENS + pos] = t;
        pair_weight[vid * TOKENS + pos] = wv;
      }
      if (lane == vid) sc = -INFINITY;
    }
    if (lane == 0) s_zt = zt;
  }
  __syncthreads();

  const float zt = s_zt;
  float* orow = out + (size_t)t * HID;
  for (int i = tid; i < HID / 4; i += 256) {
    float4 v = ((const float4*)sh)[i];
    v.x *= zt; v.y *= zt; v.z *= zt; v.w *= zt;
    ((float4*)orow)[i] = v;
  }
}

// ---------------------------------------------------------------------------
__global__ void scan_kernel(const int* __restrict__ counts,
                            int* __restrict__ offsets) {
  if (threadIdx.x == 0) {
    int acc = 0;
#pragma unroll
    for (int e = 0; e < NEXP; ++e) { offsets[e] = acc; acc += counts[e]; }
    offsets[NEXP] = acc;
  }
}

// ---------------------------------------------------------------------------
// Weight transpose+convert: src [e][R][C] fp32 -> dst [e][C][R] bf16.
// 64x64 tile; b128-only LDS with proven swz geometry. Writes <=4-way
// (free-ish), reads ~2-way. Coalesced dwordx2 in / 32B out.
// ---------------------------------------------------------------------------
__global__ __launch_bounds__(256) void transpose_cvt_kernel(
    const float* __restrict__ src, __bf16* __restrict__ dst, int R, int C)
{
  const int e = blockIdx.z, rt = blockIdx.y, ct = blockIdx.x;
  __shared__ __bf16 sT[64 * 64];  // logical [c'][r'] bf16, swz chunks

  const int tid = threadIdx.x;
  // IN: thread (fp 0..31, kg 0..7): k = kg*8+i, f-pair = fp*2.
  const int fp = tid & 31, kg = tid >> 5;
  const float* s = src + (size_t)e * R * C + (size_t)(rt * 64 + kg * 8) * C
                 + ct * 64 + fp * 2;
  float2 p[8];
#pragma unroll
  for (int i = 0; i < 8; ++i)
    p[i] = *(const float2*)(s + (size_t)i * C);

  v8bf v0, v1;
#pragma unroll
  for (int i = 0; i < 8; ++i) { v0[i] = (__bf16)p[i].x; v1[i] = (__bf16)p[i].y; }
  *(v8bf*)&sT[swz(fp * 2, kg)] = v0;      // row f, chunk kg holds k=kg*8..+7
  *(v8bf*)&sT[swz(fp * 2 + 1, kg)] = v1;
  __syncthreads();

  // OUT: thread (f = tid>>2, kq = tid&3): 16 k per thread, 32B store.
  const int f = tid >> 2, kq = tid & 3;
  const v8bf o0 = *(const v8bf*)&sT[swz(f, kq * 2)];
  const v8bf o1 = *(const v8bf*)&sT[swz(f, kq * 2 + 1)];
  __bf16* d = dst + (size_t)e * C * R + (size_t)(ct * 64 + f) * R
            + rt * 64 + kq * 16;
  *(v8bf*)d = o0;
  *(v8bf*)(d + 8) = o1;
}

// ---------------------------------------------------------------------------
// GEMM1 (grouped): tile = 128 gathered rows x 32 f (gate+up -> 64 B-rows),
// BK=64, double-buffered LDS, DMA staging with COUNTED vmcnt + raw barriers
// (T3/T4): next-tile loads stay in flight across the barrier instead of the
// compiler's vmcnt(0) drain at __syncthreads (round-8 serialization fix).
// ---------------------------------------------------------------------------
__global__ __launch_bounds__(256, 3) void gemm1_kernel(
    const __bf16* __restrict__ hbf, const __bf16* __restrict__ w13t,
    const int* __restrict__ counts, const int* __restrict__ offsets,
    const int* __restrict__ pair_token, const float* __restrict__ pair_weight,
    __bf16* __restrict__ act)
{
  const int lin = blockIdx.x;
  const int xcd = lin & 7;
  const int q = lin >> 3;
  const int mt = q & 15;
  const int g = (q >> 4) * 8 + xcd;  // (e, ft); xcd = ft&7 spreads strips
  const int ft = g & 31;
  const int e = g >> 5;

  const int cnt = counts[e];
  const int m0 = mt * 128;
  if (m0 >= cnt) return;
  const int obase = offsets[e];
  const int fbase = ft * 32;

  __shared__ __bf16 sA[2][128 * 64];  // 2 x 16 KB
  __shared__ __bf16 sB[2][64 * 64];   // 2 x 8 KB; rows 0-31 gate, 32-63 up
  __shared__ int sTok[128];
  __shared__ float sW[128];

  const int tid = threadIdx.x;
  if (tid < 128) {
    const int m = m0 + tid;
    sTok[tid] = (m < cnt) ? pair_token[e * TOKENS + m] : 0;  // dummy row 0
    sW[tid] = (m < cnt) ? pair_weight[e * TOKENS + m] : 0.f;
  }
  __syncthreads();

  const int wid = tid >> 6, lane = tid & 63;
  const int wr = wid >> 1, wf = wid & 1;
  const int lrow = lane & 15, lq = lane >> 4;

  const __bf16* gA[4];
  int ldsA[4];
#pragma unroll
  for (int i = 0; i < 4; ++i) {
    const int s = (wid * 4 + i) * 64 + lane;
    const int row = s >> 3, ch = s & 7;
    gA[i] = hbf + (size_t)sTok[row] * HID + (ch ^ (row & 7)) * 8;
    ldsA[i] = (wid * 4 + i) * 512;
  }
  const __bf16* gB[2];
  int ldsB[2];
  const __bf16* w13e = w13t + (size_t)e * (2 * FFN) * HID;
#pragma unroll
  for (int i = 0; i < 2; ++i) {
    const int s = (wid * 2 + i) * 64 + lane;
    const int row = s >> 3, ch = s & 7;
    const int fp = (row < 32) ? (fbase + row) : (FFN + fbase + (row - 32));
    gB[i] = w13e + (size_t)fp * HID + (ch ^ (row & 7)) * 8;
    ldsB[i] = (wid * 2 + i) * 512;
  }

  v4f accg[4], accu[4];
#pragma unroll
  for (int mi = 0; mi < 4; ++mi) {
    v4f z = {0.f, 0.f, 0.f, 0.f};
    accg[mi] = z; accu[mi] = z;
  }

#define G1_STAGE(buf_)                                                  \
  {                                                                     \
    _Pragma("unroll") for (int i = 0; i < 4; ++i) {                     \
      async_copy16(gA[i], &sA[buf_][ldsA[i]]); gA[i] += 64;             \
    }                                                                   \
    _Pragma("unroll") for (int i = 0; i < 2; ++i) {                     \
      async_copy16(gB[i], &sB[buf_][ldsB[i]]); gB[i] += 64;             \
    }                                                                   \
  }

  G1_STAGE(0);
  asm volatile("s_waitcnt vmcnt(0)" ::: "memory");
  __builtin_amdgcn_s_barrier();

  int buf = 0;
  const int NT = HID / 64;
  for (int t = 0; t < NT; ++t) {
    if (t < NT - 1) {
      G1_STAGE(buf ^ 1);                                // 6 DMA in flight
      asm volatile("s_waitcnt vmcnt(6)" ::: "memory");  // old tile landed
    } else {
      asm volatile("s_waitcnt vmcnt(0)" ::: "memory");  // drain final tile
    }
    __builtin_amdgcn_s_barrier();   // all waves' tile-t DMA complete

    __builtin_amdgcn_s_setprio(1);
#pragma unroll
    for (int ks = 0; ks < 2; ++ks) {
      v8bf a[4];
#pragma unroll
      for (int mi = 0; mi < 4; ++mi)
        a[mi] = *(const v8bf*)&sA[buf][swz(wr * 64 + mi * 16 + lrow, ks * 4 + lq)];
      const v8bf bg = *(const v8bf*)&sB[buf][swz(wf * 16 + lrow, ks * 4 + lq)];
      const v8bf bu = *(const v8bf*)&sB[buf][swz(32 + wf * 16 + lrow, ks * 4 + lq)];
#pragma unroll
      for (int mi = 0; mi < 4; ++mi) {
        accg[mi] = __builtin_amdgcn_mfma_f32_16x16x32_bf16(a[mi], bg, accg[mi], 0, 0, 0);
        accu[mi] = __builtin_amdgcn_mfma_f32_16x16x32_bf16(a[mi], bu, accu[mi], 0, 0, 0);
      }
    }
    __builtin_amdgcn_s_setprio(0);

    __builtin_amdgcn_s_barrier();   // reads of buf done before its overwrite
    buf ^= 1;
  }

  const int f = fbase + wf * 16 + lrow;
#pragma unroll
  for (int mi = 0; mi < 4; ++mi) {
#pragma unroll
    for (int r = 0; r < 4; ++r) {
      const int lr = wr * 64 + mi * 16 + lq * 4 + r;
      const int m = m0 + lr;
      if (m < cnt) {
        const float gg = accg[mi][r];
        const float uu = accu[mi][r];
        const float sg = gg / (1.f + __expf(-gg));
        act[(size_t)(obase + m) * FFN + f] = (__bf16)(sg * uu * sW[lr]);
      }
    }
  }
#undef G1_STAGE
}

// ---------------------------------------------------------------------------
// GEMM2 (grouped): tile = 128 rows x 64 n, BK=64, same counted-vmcnt loop.
// ---------------------------------------------------------------------------
__global__ __launch_bounds__(256, 3) void gemm2_kernel(
    const __bf16* __restrict__ act, const __bf16* __restrict__ w2t,
    const int* __restrict__ counts, const int* __restrict__ offsets,
    const int* __restrict__ pair_token, float* __restrict__ out)
{
  const int lin = blockIdx.x;
  const int xcd = lin & 7;
  const int q = lin >> 3;
  const int mt = q & 15;
  const int g = (q >> 4) * 8 + xcd;  // (e, nt)
  const int nt = g & 31;
  const int e = g >> 5;

  const int cnt = counts[e];
  const int m0 = mt * 128;
  if (m0 >= cnt) return;
  const int obase = offsets[e];
  const int n0 = nt * 64;

  __shared__ __bf16 sA[2][128 * 64];
  __shared__ __bf16 sB[2][64 * 64];
  __shared__ int sTok[128];

  const int tid = threadIdx.x;
  if (tid < 128) {
    const int m = m0 + tid;
    sTok[tid] = (m < cnt) ? pair_token[e * TOKENS + m] : -1;
  }
  __syncthreads();

  const int wid = tid >> 6, lane = tid & 63;
  const int wr = wid >> 1, wn = wid & 1;
  const int lrow = lane & 15, lq = lane >> 4;

  const __bf16* gA[4];
  int ldsA[4];
#pragma unroll
  for (int i = 0; i < 4; ++i) {
    const int s = (wid * 4 + i) * 64 + lane;
    const int row = s >> 3, ch = s & 7;
    gA[i] = act + (size_t)(obase + m0 + row) * FFN + (ch ^ (row & 7)) * 8;
    ldsA[i] = (wid * 4 + i) * 512;
  }
  const __bf16* gB[2];
  int ldsB[2];
  const __bf16* w2e = w2t + (size_t)e * HID * FFN;
#pragma unroll
  for (int i = 0; i < 2; ++i) {
    const int s = (wid * 2 + i) * 64 + lane;
    const int row = s >> 3, ch = s & 7;
    gB[i] = w2e + (size_t)(n0 + row) * FFN + (ch ^ (row & 7)) * 8;
    ldsB[i] = (wid * 2 + i) * 512;
  }

  v4f acc[4][2];
#pragma unroll
  for (int mi = 0; mi < 4; ++mi)
#pragma unroll
    for (int ni = 0; ni < 2; ++ni) {
      v4f z = {0.f, 0.f, 0.f, 0.f};
      acc[mi][ni] = z;
    }

#define G2_STAGE(buf_)                                                  \
  {                                                                     \
    _Pragma("unroll") for (int i = 0; i < 4; ++i) {                     \
      async_copy16(gA[i], &sA[buf_][ldsA[i]]); gA[i] += 64;             \
    }                                                                   \
    _Pragma("unroll") for (int i = 0; i < 2; ++i) {                     \
      async_copy16(gB[i], &sB[buf_][ldsB[i]]); gB[i] += 64;             \
    }                                                                   \
  }

  G2_STAGE(0);
  asm volatile("s_waitcnt vmcnt(0)" ::: "memory");
  __builtin_amdgcn_s_barrier();

  int buf = 0;
  const int NT = FFN / 64;
  for (int t = 0; t < NT; ++t) {
    if (t < NT - 1) {
      G2_STAGE(buf ^ 1);
      asm volatile("s_waitcnt vmcnt(6)" ::: "memory");
    } else {
      asm volatile("s_waitcnt vmcnt(0)" ::: "memory");
    }
    __builtin_amdgcn_s_barrier();

    __builtin_amdgcn_s_setprio(1);
#pragma unroll
    for (int ks = 0; ks < 2; ++ks) {
      v8bf a[4], b[2];
#pragma unroll
      for (int mi = 0; mi < 4; ++mi)
        a[mi] = *(const v8bf*)&sA[buf][swz(wr * 64 + mi * 16 + lrow, ks * 4 + lq)];
#pragma unroll
      for (int ni = 0; ni < 2; ++ni)
        b[ni] = *(const v8bf*)&sB[buf][swz(wn * 32 + ni * 16 + lrow, ks * 4 + lq)];
#pragma unroll
      for (int mi = 0; mi < 4; ++mi)
#pragma unroll
        for (int ni = 0; ni < 2; ++ni)
          acc[mi][ni] = __builtin_amdgcn_mfma_f32_16x16x32_bf16(
              a[mi], b[ni], acc[mi][ni], 0, 0, 0);
    }
    __builtin_amdgcn_s_setprio(0);

    __builtin_amdgcn_s_barrier();
    buf ^= 1;
  }

#pragma unroll
  for (int mi = 0; mi < 4; ++mi) {
#pragma unroll
    for (int ni = 0; ni < 2; ++ni) {
      const int n = n0 + wn * 32 + ni * 16 + lrow;
#pragma unroll
      for (int r = 0; r < 4; ++r) {
        const int lr = wr * 64 + mi * 16 + lq * 4 + r;
        const int m = m0 + lr;
        if (m < cnt) {
          const int t = sTok[lr];
          atomicAdd(&out[(size_t)t * HID + n], acc[mi][ni][r]);
        }
      }
    }
  }
#undef G2_STAGE
}

// ---------------------------------------------------------------------------
extern "C" void kernel_launch(void* const* d_in, const int* in_sizes, int n_in,
                              void* d_out, int out_size, void* d_ws, size_t ws_size,
                              hipStream_t stream) {
  const float* hidden = (const float*)d_in[0];
  const float* rw     = (const float*)d_in[1];
  const float* bias   = (const float*)d_in[2];
  const float* w13    = (const float*)d_in[3];
  const float* w2     = (const float*)d_in[4];
  float* out = (float*)d_out;

  char* ws = (char*)d_ws;
  int* counts = (int*)ws;
  int* offsets = (int*)(ws + 64);
  int* pair_token = (int*)(ws + 256);
  float* pair_weight = (float*)(ws + 256 + (size_t)NEXP * TOKENS * 4);
  __bf16* hbf = (__bf16*)(ws + 256 + 2 * (size_t)NEXP * TOKENS * 4);
  __bf16* act = hbf + (size_t)TOKENS * HID;
  __bf16* w13t = act + (size_t)ACT_ROWS * FFN;
  __bf16* w2t = w13t + (size_t)NEXP * (2 * FFN) * HID;

  hipMemsetAsync(counts, 0, 16 * sizeof(int), stream);
  router_kernel<<<TOKENS, 256, 0, stream>>>(hidden, rw, bias, out, hbf,
                                            counts, pair_token, pair_weight);
  scan_kernel<<<1, 64, 0, stream>>>(counts, offsets);
  transpose_cvt_kernel<<<dim3(32, 16, NEXP), 256, 0, stream>>>(w2, w2t, FFN, HID);
  transpose_cvt_kernel<<<dim3(32, 32, NEXP), 256, 0, stream>>>(w13, w13t, HID, 2 * FFN);
  gemm1_kernel<<<8192, 256, 0, stream>>>(
      hbf, w13t, counts, offsets, pair_token, pair_weight, act);
  gemm2_kernel<<<8192, 256, 0, stream>>>(
      act, w2t, counts, offsets, pair_token, out);
}

// Round 10
// 375.938 us; speedup vs baseline: 1.1545x; 1.0652x over previous
//
#include <hip/hip_runtime.h>
#include <hip/hip_bf16.h>
#include <math.h>

#define TOKENS 2048
#define HID 2048
#define FFN 1024
#define NEXP 16
#define NTOT 32
#define KSEL 4
#define RSCALE 2.5f
#define ACT_ROWS 10240  // >= max routed rows (8192) + tile overrun

typedef __bf16 v8bf __attribute__((ext_vector_type(8)));
typedef float v4f __attribute__((ext_vector_type(4)));

// Swizzled LDS addressing: row-major [rows][64] bf16 (128B rows, 8 chunks of
// 16B). Physical chunk = chunk ^ (row&7). Conflict-free b128 frag reads
// (SQ_LDS_BANK_CONFLICT == 0, rounds 2-6, 8-9).
static __device__ __forceinline__ int swz(int row, int chunk) {
  return (row << 6) + ((((unsigned)(chunk ^ row)) & 7u) << 3);
}

// Async 16B global->LDS DMA. LDS dest linear (wave base + lane*16);
// per-lane SOURCE is pre-swizzled (rule #21). Verified rounds 8-9.
static __device__ __forceinline__ void async_copy16(const __bf16* g,
                                                    __bf16* l) {
  __builtin_amdgcn_global_load_lds(
      (const __attribute__((address_space(1))) unsigned int*)g,
      (__attribute__((address_space(3))) unsigned int*)l, 16, 0, 0);
}

// ---------------------------------------------------------------------------
// Router: one block per token (unchanged, correct since round 1).
// ---------------------------------------------------------------------------
__global__ __launch_bounds__(256) void router_kernel(
    const float* __restrict__ hidden, const float* __restrict__ rw,
    const float* __restrict__ bias, float* __restrict__ out,
    __bf16* __restrict__ hbf,
    int* __restrict__ counts, int* __restrict__ pair_token,
    float* __restrict__ pair_weight)
{
  const int t = blockIdx.x;
  const int tid = threadIdx.x;
  __shared__ float sh[HID];
  __shared__ float part[8][NTOT];
  __shared__ float s_zt;

  const float* hrow = hidden + (size_t)t * HID;
  for (int i = tid; i < HID / 4; i += 256)
    ((float4*)sh)[i] = ((const float4*)hrow)[i];
  __syncthreads();

  {
    const int base = tid * 8;
    v8bf v;
#pragma unroll
    for (int j = 0; j < 8; ++j) v[j] = (__bf16)sh[base + j];
    *(v8bf*)(hbf + (size_t)t * HID + base) = v;
  }

  {
    const int g = tid >> 5, e = tid & 31;
    const float* w = rw + (size_t)e * HID + g * 256;
    const float* hh = sh + g * 256;
    float acc = 0.f;
#pragma unroll 8
    for (int h = 0; h < 256; ++h) acc = fmaf(hh[h], w[h], acc);
    part[g][e] = acc;
  }
  __syncthreads();

  if (tid < 64) {
    const int lane = tid;
    float logit = -INFINITY;
    if (lane < NTOT) {
      float s = 0.f;
#pragma unroll
      for (int g = 0; g < 8; ++g) s += part[g][lane];
      logit = s;
    }
    float m = logit;
#pragma unroll
    for (int off = 32; off; off >>= 1) m = fmaxf(m, __shfl_xor(m, off));
    const float ex = (lane < NTOT) ? expf(logit - m) : 0.f;
    float sum = ex;
#pragma unroll
    for (int off = 32; off; off >>= 1) sum += __shfl_xor(sum, off);
    float sc = (lane < NTOT) ? (ex / sum + bias[lane]) : -INFINITY;

    float zt = 0.f;
#pragma unroll
    for (int it = 0; it < KSEL; ++it) {
      float v = sc; int vid = lane;
#pragma unroll
      for (int off = 32; off; off >>= 1) {
        const float ov = __shfl_xor(v, off);
        const int oid = __shfl_xor(vid, off);
        if (ov > v || (ov == v && oid < vid)) { v = ov; vid = oid; }
      }
      const float wv = v * RSCALE;
      if (vid >= NEXP) {
        zt += wv;
      } else if (lane == 0) {
        const int pos = atomicAdd(&counts[vid], 1);
        pair_token[vid * TOKENS + pos] = t;
        pair_weight[vid * TOKENS + pos] = wv;
      }
      if (lane == vid) sc = -INFINITY;
    }
    if (lane == 0) s_zt = zt;
  }
  __syncthreads();

  const float zt = s_zt;
  float* orow = out + (size_t)t * HID;
  for (int i = tid; i < HID / 4; i += 256) {
    float4 v = ((const float4*)sh)[i];
    v.x *= zt; v.y *= zt; v.z *= zt; v.w *= zt;
    ((float4*)orow)[i] = v;
  }
}

// ---------------------------------------------------------------------------
__global__ void scan_kernel(const int* __restrict__ counts,
                            int* __restrict__ offsets) {
  if (threadIdx.x == 0) {
    int acc = 0;
#pragma unroll
    for (int e = 0; e < NEXP; ++e) { offsets[e] = acc; acc += counts[e]; }
    offsets[NEXP] = acc;
  }
}

// ---------------------------------------------------------------------------
// Weight transpose+convert: src [e][R][C] fp32 -> dst [e][C][R] bf16.
// 64x64 tile; b128-only LDS, proven swz geometry (round 9).
// ---------------------------------------------------------------------------
__global__ __launch_bounds__(256) void transpose_cvt_kernel(
    const float* __restrict__ src, __bf16* __restrict__ dst, int R, int C)
{
  const int e = blockIdx.z, rt = blockIdx.y, ct = blockIdx.x;
  __shared__ __bf16 sT[64 * 64];

  const int tid = threadIdx.x;
  const int fp = tid & 31, kg = tid >> 5;
  const float* s = src + (size_t)e * R * C + (size_t)(rt * 64 + kg * 8) * C
                 + ct * 64 + fp * 2;
  float2 p[8];
#pragma unroll
  for (int i = 0; i < 8; ++i)
    p[i] = *(const float2*)(s + (size_t)i * C);

  v8bf v0, v1;
#pragma unroll
  for (int i = 0; i < 8; ++i) { v0[i] = (__bf16)p[i].x; v1[i] = (__bf16)p[i].y; }
  *(v8bf*)&sT[swz(fp * 2, kg)] = v0;
  *(v8bf*)&sT[swz(fp * 2 + 1, kg)] = v1;
  __syncthreads();

  const int f = tid >> 2, kq = tid & 3;
  const v8bf o0 = *(const v8bf*)&sT[swz(f, kq * 2)];
  const v8bf o1 = *(const v8bf*)&sT[swz(f, kq * 2 + 1)];
  __bf16* d = dst + (size_t)e * C * R + (size_t)(ct * 64 + f) * R
            + rt * 64 + kq * 16;
  *(v8bf*)d = o0;
  *(v8bf*)(d + 8) = o1;
}

// ---------------------------------------------------------------------------
// GEMM1 (grouped): m97 geometry. Tile = 128 gathered rows x 64 f (gate+up
// interleaved as 128 B-rows), BK=64. Per wave per K-step: 32 MFMA / 16
// ds_read_b128 / 8 DMA (m97's exact ratio; round-9's was 2-3x worse).
// Counted vmcnt(8) + raw barriers; LDS 64KB -> 2 blocks/CU.
// B-row layout: r = half*64 + gu*32 + (f&31), half = f>>5 (per-wave swiglu).
// ---------------------------------------------------------------------------
__global__ __launch_bounds__(256, 2) void gemm1_kernel(
    const __bf16* __restrict__ hbf, const __bf16* __restrict__ w13t,
    const int* __restrict__ counts, const int* __restrict__ offsets,
    const int* __restrict__ pair_token, const float* __restrict__ pair_weight,
    __bf16* __restrict__ act)
{
  const int lin = blockIdx.x;
  const int xcd = lin & 7;
  const int q = lin >> 3;
  const int mt = q & 15;             // dense: m-tiles share the (e,ft) B-panel
  const int g = (q >> 4) * 8 + xcd;  // 0..255 = (e, ft) pinned per XCD
  const int ft = g & 15;
  const int e = g >> 4;

  const int cnt = counts[e];
  const int m0 = mt * 128;
  if (m0 >= cnt) return;
  const int obase = offsets[e];
  const int fbase = ft * 64;

  __shared__ __bf16 sA[2][128 * 64];  // 2 x 16 KB
  __shared__ __bf16 sB[2][128 * 64];  // 2 x 16 KB
  __shared__ int sTok[128];
  __shared__ float sW[128];

  const int tid = threadIdx.x;
  if (tid < 128) {
    const int m = m0 + tid;
    sTok[tid] = (m < cnt) ? pair_token[e * TOKENS + m] : 0;  // dummy row 0
    sW[tid] = (m < cnt) ? pair_weight[e * TOKENS + m] : 0.f;
  }
  __syncthreads();

  const int wid = tid >> 6, lane = tid & 63;
  const int wr = wid >> 1, wf = wid & 1;
  const int lrow = lane & 15, lq = lane >> 4;

  // DMA maps: 1024 slots of 16B per operand; slot s: row=s>>3, ch=s&7.
  const __bf16* gA[4];
  const __bf16* gB[4];
  int ldsO[4];
  const __bf16* w13e = w13t + (size_t)e * (2 * FFN) * HID;
#pragma unroll
  for (int i = 0; i < 4; ++i) {
    const int s = (wid * 4 + i) * 64 + lane;
    const int row = s >> 3, ch = s & 7;
    ldsO[i] = (wid * 4 + i) * 512;
    gA[i] = hbf + (size_t)sTok[row] * HID + (ch ^ (row & 7)) * 8;
    // B-row r -> w13t row: f = fbase + (r>>6)*32 + (r&31); gu = (r>>5)&1
    const int f = fbase + ((row >> 6) << 5) + (row & 31);
    const int gu = (row >> 5) & 1;
    gB[i] = w13e + (size_t)(gu * FFN + f) * HID + (ch ^ (row & 7)) * 8;
  }

  v4f accg[4][2], accu[4][2];
#pragma unroll
  for (int mi = 0; mi < 4; ++mi)
#pragma unroll
    for (int ni = 0; ni < 2; ++ni) {
      v4f z = {0.f, 0.f, 0.f, 0.f};
      accg[mi][ni] = z; accu[mi][ni] = z;
    }

#define G1_STAGE(buf_)                                                  \
  {                                                                     \
    _Pragma("unroll") for (int i = 0; i < 4; ++i) {                     \
      async_copy16(gA[i], &sA[buf_][ldsO[i]]); gA[i] += 64;             \
    }                                                                   \
    _Pragma("unroll") for (int i = 0; i < 4; ++i) {                     \
      async_copy16(gB[i], &sB[buf_][ldsO[i]]); gB[i] += 64;             \
    }                                                                   \
  }

  G1_STAGE(0);
  asm volatile("s_waitcnt vmcnt(0)" ::: "memory");
  __builtin_amdgcn_s_barrier();

  int buf = 0;
  const int NT = HID / 64;
  for (int t = 0; t < NT; ++t) {
    if (t < NT - 1) {
      G1_STAGE(buf ^ 1);                                // 8 new DMA in flight
      asm volatile("s_waitcnt vmcnt(8)" ::: "memory");  // tile-t landed
    } else {
      asm volatile("s_waitcnt vmcnt(0)" ::: "memory");
    }
    __builtin_amdgcn_s_barrier();

    __builtin_amdgcn_s_setprio(1);
#pragma unroll
    for (int ks = 0; ks < 2; ++ks) {
      v8bf a[4], bg[2], bu[2];
#pragma unroll
      for (int mi = 0; mi < 4; ++mi)
        a[mi] = *(const v8bf*)&sA[buf][swz(wr * 64 + mi * 16 + lrow, ks * 4 + lq)];
#pragma unroll
      for (int ni = 0; ni < 2; ++ni) {
        bg[ni] = *(const v8bf*)&sB[buf][swz(wf * 64 + ni * 16 + lrow, ks * 4 + lq)];
        bu[ni] = *(const v8bf*)&sB[buf][swz(wf * 64 + 32 + ni * 16 + lrow, ks * 4 + lq)];
      }
#pragma unroll
      for (int mi = 0; mi < 4; ++mi)
#pragma unroll
        for (int ni = 0; ni < 2; ++ni) {
          accg[mi][ni] = __builtin_amdgcn_mfma_f32_16x16x32_bf16(
              a[mi], bg[ni], accg[mi][ni], 0, 0, 0);
          accu[mi][ni] = __builtin_amdgcn_mfma_f32_16x16x32_bf16(
              a[mi], bu[ni], accu[mi][ni], 0, 0, 0);
        }
    }
    __builtin_amdgcn_s_setprio(0);

    __builtin_amdgcn_s_barrier();
    buf ^= 1;
  }

  // ---- epilogue: swiglu, fold routing weight, store act (bf16) ----
#pragma unroll
  for (int mi = 0; mi < 4; ++mi) {
#pragma unroll
    for (int ni = 0; ni < 2; ++ni) {
      const int f = fbase + wf * 32 + ni * 16 + lrow;
#pragma unroll
      for (int r = 0; r < 4; ++r) {
        const int lr = wr * 64 + mi * 16 + lq * 4 + r;
        const int m = m0 + lr;
        if (m < cnt) {
          const float gg = accg[mi][ni][r];
          const float uu = accu[mi][ni][r];
          const float sg = gg / (1.f + __expf(-gg));
          act[(size_t)(obase + m) * FFN + f] = (__bf16)(sg * uu * sW[lr]);
        }
      }
    }
  }
#undef G1_STAGE
}

// ---------------------------------------------------------------------------
// GEMM2 (grouped): m97 geometry. Tile = 128 rows x 128 n, BK=64, K=1024.
// Same counted-vmcnt loop. atomicAdd into out.
// ---------------------------------------------------------------------------
__global__ __launch_bounds__(256, 2) void gemm2_kernel(
    const __bf16* __restrict__ act, const __bf16* __restrict__ w2t,
    const int* __restrict__ counts, const int* __restrict__ offsets,
    const int* __restrict__ pair_token, float* __restrict__ out)
{
  const int lin = blockIdx.x;
  const int xcd = lin & 7;
  const int q = lin >> 3;
  const int mt = q & 15;
  const int g = (q >> 4) * 8 + xcd;  // 0..255 = (e, nt)
  const int nt = g & 15;
  const int e = g >> 4;

  const int cnt = counts[e];
  const int m0 = mt * 128;
  if (m0 >= cnt) return;
  const int obase = offsets[e];
  const int n0 = nt * 128;

  __shared__ __bf16 sA[2][128 * 64];
  __shared__ __bf16 sB[2][128 * 64];
  __shared__ int sTok[128];

  const int tid = threadIdx.x;
  if (tid < 128) {
    const int m = m0 + tid;
    sTok[tid] = (m < cnt) ? pair_token[e * TOKENS + m] : -1;
  }
  __syncthreads();

  const int wid = tid >> 6, lane = tid & 63;
  const int wr = wid >> 1, wn = wid & 1;
  const int lrow = lane & 15, lq = lane >> 4;

  const __bf16* gA[4];
  const __bf16* gB[4];
  int ldsO[4];
  const __bf16* w2e = w2t + (size_t)e * HID * FFN;
#pragma unroll
  for (int i = 0; i < 4; ++i) {
    const int s = (wid * 4 + i) * 64 + lane;
    const int row = s >> 3, ch = s & 7;
    ldsO[i] = (wid * 4 + i) * 512;
    gA[i] = act + (size_t)(obase + m0 + row) * FFN + (ch ^ (row & 7)) * 8;
    gB[i] = w2e + (size_t)(n0 + row) * FFN + (ch ^ (row & 7)) * 8;
  }

  v4f acc[4][4];
#pragma unroll
  for (int mi = 0; mi < 4; ++mi)
#pragma unroll
    for (int ni = 0; ni < 4; ++ni) {
      v4f z = {0.f, 0.f, 0.f, 0.f};
      acc[mi][ni] = z;
    }

#define G2_STAGE(buf_)                                                  \
  {                                                                     \
    _Pragma("unroll") for (int i = 0; i < 4; ++i) {                     \
      async_copy16(gA[i], &sA[buf_][ldsO[i]]); gA[i] += 64;             \
    }                                                                   \
    _Pragma("unroll") for (int i = 0; i < 4; ++i) {                     \
      async_copy16(gB[i], &sB[buf_][ldsO[i]]); gB[i] += 64;             \
    }                                                                   \
  }

  G2_STAGE(0);
  asm volatile("s_waitcnt vmcnt(0)" ::: "memory");
  __builtin_amdgcn_s_barrier();

  int buf = 0;
  const int NT = FFN / 64;
  for (int t = 0; t < NT; ++t) {
    if (t < NT - 1) {
      G2_STAGE(buf ^ 1);
      asm volatile("s_waitcnt vmcnt(8)" ::: "memory");
    } else {
      asm volatile("s_waitcnt vmcnt(0)" ::: "memory");
    }
    __builtin_amdgcn_s_barrier();

    __builtin_amdgcn_s_setprio(1);
#pragma unroll
    for (int ks = 0; ks < 2; ++ks) {
      v8bf a[4], b[4];
#pragma unroll
      for (int mi = 0; mi < 4; ++mi)
        a[mi] = *(const v8bf*)&sA[buf][swz(wr * 64 + mi * 16 + lrow, ks * 4 + lq)];
#pragma unroll
      for (int ni = 0; ni < 4; ++ni)
        b[ni] = *(const v8bf*)&sB[buf][swz(wn * 64 + ni * 16 + lrow, ks * 4 + lq)];
#pragma unroll
      for (int mi = 0; mi < 4; ++mi)
#pragma unroll
        for (int ni = 0; ni < 4; ++ni)
          acc[mi][ni] = __builtin_amdgcn_mfma_f32_16x16x32_bf16(
              a[mi], b[ni], acc[mi][ni], 0, 0, 0);
    }
    __builtin_amdgcn_s_setprio(0);

    __builtin_amdgcn_s_barrier();
    buf ^= 1;
  }

  // ---- epilogue: atomicAdd weighted expert output into out ----
#pragma unroll
  for (int mi = 0; mi < 4; ++mi) {
#pragma unroll
    for (int ni = 0; ni < 4; ++ni) {
      const int n = n0 + wn * 64 + ni * 16 + lrow;
#pragma unroll
      for (int r = 0; r < 4; ++r) {
        const int lr = wr * 64 + mi * 16 + lq * 4 + r;
        const int m = m0 + lr;
        if (m < cnt) {
          const int t = sTok[lr];
          atomicAdd(&out[(size_t)t * HID + n], acc[mi][ni][r]);
        }
      }
    }
  }
#undef G2_STAGE
}

// ---------------------------------------------------------------------------
extern "C" void kernel_launch(void* const* d_in, const int* in_sizes, int n_in,
                              void* d_out, int out_size, void* d_ws, size_t ws_size,
                              hipStream_t stream) {
  const float* hidden = (const float*)d_in[0];
  const float* rw     = (const float*)d_in[1];
  const float* bias   = (const float*)d_in[2];
  const float* w13    = (const float*)d_in[3];
  const float* w2     = (const float*)d_in[4];
  float* out = (float*)d_out;

  char* ws = (char*)d_ws;
  int* counts = (int*)ws;
  int* offsets = (int*)(ws + 64);
  int* pair_token = (int*)(ws + 256);
  float* pair_weight = (float*)(ws + 256 + (size_t)NEXP * TOKENS * 4);
  __bf16* hbf = (__bf16*)(ws + 256 + 2 * (size_t)NEXP * TOKENS * 4);
  __bf16* act = hbf + (size_t)TOKENS * HID;
  __bf16* w13t = act + (size_t)ACT_ROWS * FFN;
  __bf16* w2t = w13t + (size_t)NEXP * (2 * FFN) * HID;

  hipMemsetAsync(counts, 0, 16 * sizeof(int), stream);
  router_kernel<<<TOKENS, 256, 0, stream>>>(hidden, rw, bias, out, hbf,
                                            counts, pair_token, pair_weight);
  scan_kernel<<<1, 64, 0, stream>>>(counts, offsets);
  transpose_cvt_kernel<<<dim3(32, 16, NEXP), 256, 0, stream>>>(w2, w2t, FFN, HID);
  transpose_cvt_kernel<<<dim3(32, 32, NEXP), 256, 0, stream>>>(w13, w13t, HID, 2 * FFN);
  // gemm1: 8 xcd x 16 mt x 32 ghi = 4096 blocks (groups = 16e x 16ft)
  gemm1_kernel<<<4096, 256, 0, stream>>>(
      hbf, w13t, counts, offsets, pair_token, pair_weight, act);
  // gemm2: 8 xcd x 16 mt x 32 ghi = 4096 blocks (groups = 16e x 16nt)
  gemm2_kernel<<<4096, 256, 0, stream>>>(
      act, w2t, counts, offsets, pair_token, out);
}